// Round 4
// baseline (42.288 us; speedup 1.0000x reference)
//
#include <hip/hip_runtime.h>

// Problem constants (from reference)
constexpr int NC = 2;   // N_CLASSES
constexpr int NF = 10;  // N_FEATURES
constexpr int PD = 10;  // PSI_DIM

constexpr int THREADS = 256;
constexpr int NWAVES = THREADS / 64;
constexpr int TILE_ROWS = 64;                     // 1 row per lane per tile
constexpr int TILE_F4 = TILE_ROWS * NF / 4;       // 160 float4 = 2560 B
constexpr int TILE_FLOATS = TILE_ROWS * NF;       // 640 floats

// Barrier-free, per-wave double-buffered streaming kernel at 32 waves/CU.
//  - Each wave owns a private 2x2560B LDS region; no cross-wave deps -> no s_barrier.
//  - Stage via global_load_lds width=16 (2 full-wave + 1 half-wave instr per tile).
//  - Counted s_waitcnt vmcnt(N), never 0 in steady state (T4).
//  - M_r broadcast per-wave via __shfl (no LDS, no __syncthreads).
//  LDS: 4 waves * 2 bufs * 2560 B = 20480 B exactly -> 8 blocks/CU.
__global__ __launch_bounds__(THREADS, 8) void fused_stream_kernel(
        const float* __restrict__ x,
        const float* __restrict__ psi_r,
        const float* __restrict__ psi_i,
        const float* __restrict__ A_r,
        const float* __restrict__ A_i,
        float* __restrict__ out,
        int nTiles) {
    __shared__ float tile[NWAVES][2][TILE_FLOATS];   // 20480 B total

    const int t = threadIdx.x;
    const int w = t >> 6;
    const int l = t & 63;

    // ---- M_r[k,a] = sum_{i,j} (pr_i*Ar[k,i,j,a] - pi_i*Ai[k,i,j,a]) * (pr_j - pi_j)
    // Lanes 0..19 compute one (k,a) each; broadcast wave-wide via shfl.
    float acc = 0.f;
    if (l < NC * NF) {
        const int kk = l / NF;
        const int a = l - kk * NF;
        for (int i = 0; i < PD; ++i) {
            float pri = psi_r[i], pii = psi_i[i];
#pragma unroll
            for (int j = 0; j < PD; ++j) {
                float dj = psi_r[j] - psi_i[j];
                int idx = ((kk * PD + i) * PD + j) * NF + a;
                acc = fmaf(pri * A_r[idx] - pii * A_i[idx], dj, acc);
            }
        }
    }
    float m0[NF], m1[NF];
#pragma unroll
    for (int a = 0; a < NF; ++a) {
        m0[a] = __shfl(acc, a);
        m1[a] = __shfl(acc, NF + a);
    }

    const float4* x4 = reinterpret_cast<const float4*>(x);
    float2* out2 = reinterpret_cast<float2*>(out);
    const int W = (int)gridDim.x * NWAVES;
    const int gw = (int)blockIdx.x * NWAVES + w;

    // Stage tile tk (64 rows = 160 float4) into wave-private buf.
    // 2 full-wave + 1 half-wave global_load_lds (3 vmcnt events), coalesced,
    // linear LDS dest (HW adds laneId*16B to the wave-uniform base).
    auto STAGE = [&](int buf, int tk) {
        const float* dst = &tile[w][buf][0];
        const float4* src = x4 + (long)tk * TILE_F4;
        __builtin_amdgcn_global_load_lds(
            (const __attribute__((address_space(1))) void*)(src + l),
            (__attribute__((address_space(3))) void*)dst, 16, 0, 0);
        __builtin_amdgcn_global_load_lds(
            (const __attribute__((address_space(1))) void*)(src + 64 + l),
            (__attribute__((address_space(3))) void*)(dst + 256), 16, 0, 0);
        if (l < 32) {
            __builtin_amdgcn_global_load_lds(
                (const __attribute__((address_space(1))) void*)(src + 128 + l),
                (__attribute__((address_space(3))) void*)(dst + 512), 16, 0, 0);
        }
    };

    if (gw >= nTiles) return;

    STAGE(0, gw);
    int cur = 0;
    int iter = 0;
    for (int k = gw; k < nTiles; k += W, ++iter) {
        const int kn = k + W;
        const bool hasNext = kn < nTiles;
        if (hasNext) STAGE(cur ^ 1, kn);

        // FIFO: [3 loads(tile k)] [store(k-1) if iter>0] [3 loads(tile k+1) if hasNext]
        // Retire tile k's loads; keep the newer ops in flight. Never vmcnt(0) mid-loop.
        const int n = (hasNext ? 3 : 0) + (iter ? 1 : 0);
        if (n == 4)      asm volatile("s_waitcnt vmcnt(4)" ::: "memory");
        else if (n == 3) asm volatile("s_waitcnt vmcnt(3)" ::: "memory");
        else if (n == 1) asm volatile("s_waitcnt vmcnt(1)" ::: "memory");
        else             asm volatile("s_waitcnt vmcnt(0)" ::: "memory");

        // ---- compute: one row (10 floats, 40B, 8B-aligned) per lane ----
        const float* row = &tile[w][cur][l * NF];
        float o0 = 0.f, o1 = 0.f;
#pragma unroll
        for (int a = 0; a < NF; ++a) {
            float f = row[a];
            o0 = fmaf(f, m0[a], o0);
            o1 = fmaf(f, m1[a], o1);
        }
        out2[(long)k * TILE_ROWS + l] = make_float2(o0, o1);

        cur ^= 1;
    }
}

extern "C" void kernel_launch(void* const* d_in, const int* in_sizes, int n_in,
                              void* d_out, int out_size, void* d_ws, size_t ws_size,
                              hipStream_t stream) {
    const float* x     = (const float*)d_in[0];
    const float* psi_r = (const float*)d_in[1];
    const float* psi_i = (const float*)d_in[2];
    const float* A_r   = (const float*)d_in[3];
    const float* A_i   = (const float*)d_in[4];
    float* out = (float*)d_out;

    const int T = in_sizes[0] / NF;          // 4,000,000 rows (divisible by 64)
    const int nTiles = T / TILE_ROWS;        // 62,500 tiles of 64 rows

    // 8 blocks/CU x 256 CU = 2048 persistent blocks (32 waves/CU, LDS = 20 KB/block).
    int blocks = 8 * 256;
    if (blocks > nTiles / NWAVES + 1) blocks = nTiles / NWAVES + 1;

    fused_stream_kernel<<<blocks, THREADS, 0, stream>>>(
        x, psi_r, psi_i, A_r, A_i, out, nTiles);
}

// Round 5
// 32.827 us; speedup vs baseline: 1.2882x; 1.2882x over previous
//
#include <hip/hip_runtime.h>

// Problem constants (from reference)
constexpr int NC = 2;   // N_CLASSES
constexpr int NF = 10;  // N_FEATURES
constexpr int PD = 10;  // PSI_DIM

constexpr int THREADS = 256;
constexpr int NWAVES = THREADS / 64;
constexpr int ROWS_PW = 64;                 // rows per wave-tile (1 row/lane)
constexpr int TFLOATS = ROWS_PW * NF;       // 640 floats = 2560 B
constexpr int TF4 = TFLOATS / 4;            // 160 float4

// Barrier-free steady-state streaming at 32 waves/CU:
//  - per-wave private double-buffered LDS tiles (no cross-wave deps after prologue)
//  - global_load_lds width=16, counted s_waitcnt vmcnt(N) (never 0 mid-loop)
//  - M_r in SGPRs (readfirstlane) -> ~30 VGPR, no spills at launch_bounds(256,8)
//  - M scratch overlaid on tile[0][1] so LDS = 20480 B exactly -> 8 blocks/CU
__global__ __launch_bounds__(THREADS, 8) void fused_stream_kernel(
        const float* __restrict__ x,
        const float* __restrict__ psi_r,
        const float* __restrict__ psi_i,
        const float* __restrict__ A_r,
        const float* __restrict__ A_i,
        float* __restrict__ out,
        int nTiles) {
    __shared__ float tile[NWAVES][2][TFLOATS];   // 20480 B exactly

    const int t = threadIdx.x;
    const int w = t >> 6;
    const int l = t & 63;

    const float4* x4 = reinterpret_cast<const float4*>(x);
    float2* out2 = reinterpret_cast<float2*>(out);
    const int W = (int)gridDim.x * NWAVES;
    const int gw = (int)blockIdx.x * NWAVES + w;

    auto STAGE = [&](int buf, int tk) {
        const float* dst = &tile[w][buf][0];
        const float4* src = x4 + (long)tk * TF4;
        __builtin_amdgcn_global_load_lds(
            (const __attribute__((address_space(1))) void*)(src + l),
            (__attribute__((address_space(3))) void*)dst, 16, 0, 0);
        __builtin_amdgcn_global_load_lds(
            (const __attribute__((address_space(1))) void*)(src + 64 + l),
            (__attribute__((address_space(3))) void*)(dst + 256), 16, 0, 0);
        if (l < 32) {
            __builtin_amdgcn_global_load_lds(
                (const __attribute__((address_space(1))) void*)(src + 128 + l),
                (__attribute__((address_space(3))) void*)(dst + 512), 16, 0, 0);
        }
    };

    // Issue tile-0 stage immediately; its HBM latency hides under the M phase.
    if (gw < nTiles) STAGE(0, gw);

    // ---- M_r[k,a] = sum_{i,j} (pr_i*Ar[k,i,j,a] - pi_i*Ai[k,i,j,a])*(pr_j - pi_j)
    // Scratch (220 floats) overlaid on tile[0][1] (wave 0, buf 1) — untouched by
    // any STAGE until the loop's first STAGE(buf=1), which is after the last sync.
    float* part = &tile[0][1][0];     // [200] i-partials
    float* Msh  = part + NC * NF * PD; // [20]
    if (t < NC * NF * PD) {
        const int k = t / (NF * PD);
        const int rem = t - k * (NF * PD);
        const int a = rem / PD;
        const int i = rem - a * PD;
        const float pri = psi_r[i], pii = psi_i[i];
        float acc = 0.f;
#pragma unroll
        for (int j = 0; j < PD; ++j) {
            float dj = psi_r[j] - psi_i[j];
            int idx = ((k * PD + i) * PD + j) * NF + a;
            acc = fmaf(pri * A_r[idx] - pii * A_i[idx], dj, acc);
        }
        part[(k * NF + a) * PD + i] = acc;
    }
    __syncthreads();
    if (t < NC * NF) {
        float s = 0.f;
#pragma unroll
        for (int i = 0; i < PD; ++i) s += part[t * PD + i];
        Msh[t] = s;
    }
    __syncthreads();

    // Broadcast M into SGPRs (uniform LDS read + readfirstlane).
    float sm0[NF], sm1[NF];
#pragma unroll
    for (int a = 0; a < NF; ++a) {
        sm0[a] = __int_as_float(__builtin_amdgcn_readfirstlane(__float_as_int(Msh[a])));
        sm1[a] = __int_as_float(__builtin_amdgcn_readfirstlane(__float_as_int(Msh[NF + a])));
    }
    // All waves must finish reading Msh before wave 0 can overwrite tile[0][1].
    __syncthreads();

    if (gw >= nTiles) return;

    int cur = 0;
    int iter = 0;
    for (int k = gw; k < nTiles; k += W, ++iter) {
        const int kn = k + W;
        const bool hasNext = kn < nTiles;
        if (hasNext) STAGE(cur ^ 1, kn);

        // FIFO: [3 loads(k)] [store(k-1) if iter>0] [3 loads(k+1) if hasNext].
        // Retire tile k's loads, keep newer ops in flight. Never vmcnt(0) mid-loop.
        const int n = (hasNext ? 3 : 0) + (iter ? 1 : 0);
        if (n == 4)      asm volatile("s_waitcnt vmcnt(4)" ::: "memory");
        else if (n == 3) asm volatile("s_waitcnt vmcnt(3)" ::: "memory");
        else if (n == 1) asm volatile("s_waitcnt vmcnt(1)" ::: "memory");
        else             asm volatile("s_waitcnt vmcnt(0)" ::: "memory");

        // ---- compute: one row (10 floats, 40 B) per lane; M from SGPRs ----
        const float* row = &tile[w][cur][l * NF];
        float o0 = 0.f, o1 = 0.f;
#pragma unroll
        for (int a = 0; a < NF; ++a) {
            const float f = row[a];
            o0 = fmaf(f, sm0[a], o0);
            o1 = fmaf(f, sm1[a], o1);
        }
        out2[(long)k * ROWS_PW + l] = make_float2(o0, o1);

        asm volatile("" ::: "memory");  // pin store issue before next iteration
        cur ^= 1;
    }
}

extern "C" void kernel_launch(void* const* d_in, const int* in_sizes, int n_in,
                              void* d_out, int out_size, void* d_ws, size_t ws_size,
                              hipStream_t stream) {
    const float* x     = (const float*)d_in[0];
    const float* psi_r = (const float*)d_in[1];
    const float* psi_i = (const float*)d_in[2];
    const float* A_r   = (const float*)d_in[3];
    const float* A_i   = (const float*)d_in[4];
    float* out = (float*)d_out;

    const int T = in_sizes[0] / NF;          // 4,000,000 rows (divisible by 64)
    const int nTiles = T / ROWS_PW;          // 62,500 wave-tiles

    // 8 blocks/CU x 256 CU (LDS = 20480 B/block -> exactly 8 fit; 32 waves/CU).
    int blocks = 8 * 256;
    int maxBlocks = (nTiles + NWAVES - 1) / NWAVES;
    if (blocks > maxBlocks) blocks = maxBlocks;

    fused_stream_kernel<<<blocks, THREADS, 0, stream>>>(
        x, psi_r, psi_i, A_r, A_i, out, nTiles);
}